// Round 13
// baseline (149.046 us; speedup 1.0000x reference)
//
#include <hip/hip_runtime.h>

#define NWIN 4096
#define EPSF 1e-6f
#define BLOCK_MAIN 512
#define NWAVES (BLOCK_MAIN / 64)
#define SEGW (3 * NWIN)          // packed: [wi*3] = cnt<<24|p*2^16, [+1] rate, [+2] pd

// fixed-point scales
#define SCALE_P   65536.0f       // 2^16  sum_p (packed low 24 bits of word0)
#define SCALE_R   131072.0f      // 2^17  agg_rate / sum_pd
#define INV_P     (1.0/65536.0)
#define INV_R     (1.0/131072.0)

// ---------------- workspace layout (bytes) ----------------
//  byte 0: double ce_num   byte 8: double ce_den
//  byte 16: u32 n_valid(u[4]) byte 20: u32 n_mask(u[5])
//  byte 24: f32 ref_dobs(f[6]) byte 28: f32 frac(f[7])
//  byte 32,36: u32 prefixes(u[8],u[9])  byte 40,44: u32 ranks(u[10],u[11])
#define OFF_SEGU  256            // u32 g_seg_u32[16384]  [wi*4+c] unpacked
#define OFF_H1    65792          // u32[2048]
#define OFF_H2    73984          // u32[2*2048]
#define OFF_H3    90368          // u32[2*1024]
#define OFF_CEP   98560          // float ce_part[768*8] (24 KB, ends 123136)
#define OFF_PART  131072         // part (grid x 48KB) | keys

__device__ __forceinline__ unsigned make_key_raw(const float2* __restrict__ xzw,
                                                 const int* __restrict__ mask,
                                                 const int* __restrict__ widx, int i)
{
    int wi = widx[i];
    int m = mask[i];
    if (wi < 0 || !m) return 0x7F800000u;
    float d = fmaxf(xzw[2 * i + 1].x, 0.0f);
    unsigned k = __float_as_uint(d);
    return (k == 0x80000000u) ? 0u : k;
}

// ---------------- per-element fused work (branchless, packed LDS) ----------------
__device__ __forceinline__ void process_elem(
    float lgx, float lgy, int yi, int mi, float xz, float xw, int wi,
    float cw0, float cw1, unsigned* keyOut,
    float& num, float& den, unsigned& nv, unsigned& nm, unsigned& zc,
    unsigned* s_seg, unsigned* s_h1)
{
    float d = lgx - lgy;
    float ad = fabsf(d);
    float t = __expf(-ad);
    float inv1t = 1.0f / (1.0f + t);
    float l1p = __logf(1.0f + t);
    float s = yi ? d : -d;
    float nll = fmaxf(s, 0.0f) + l1p;
    float maskf = mi ? 1.0f : 0.0f;
    float wy = (yi ? cw1 : cw0) * maskf;
    nm += (mi != 0);
    num += wy * nll;
    den += wy;

    bool vq = (wi >= 0) && mi;
    float dob = fmaxf(xz, 0.0f);
    unsigned kraw = __float_as_uint(dob);
    kraw = (kraw == 0x80000000u) ? 0u : kraw;
    unsigned key = vq ? kraw : 0x7F800000u;
    *keyOut = key;
    nv += vq;
    zc += (key == 0u);

    // hist1: u16-packed pairs; zeros add 0
    unsigned hb = key >> 21;
    atomicAdd(&s_h1[hb >> 1], (key != 0u) ? (1u << ((hb & 1u) << 4)) : 0u);

    // segment sums, packed word0 = cnt<<24 | p*2^16 (invalid adds 0 to window 0)
    bool sv = vq && ((unsigned)wi < NWIN);
    unsigned b = sv ? ((unsigned)wi * 3u) : 0u;
    float p = ((d > 0.0f) ? t : 1.0f) * inv1t;
    float rate = fmaxf(xw, 0.0f);
    unsigned a0 = sv ? ((1u << 24) | (unsigned)(p * SCALE_P + 0.5f)) : 0u;
    unsigned a1 = sv ? (unsigned)(p * rate * SCALE_R + 0.5f) : 0u;
    unsigned a2 = sv ? (unsigned)(p * dob * SCALE_R + 0.5f) : 0u;
    atomicAdd(&s_seg[b], a0);
    atomicAdd(&s_seg[b + 1], a1);
    atomicAdd(&s_seg[b + 2], a2);
}

// ---------------- main fused pass ----------------
extern "C" __global__ __launch_bounds__(BLOCK_MAIN)
void k_main(const float2* __restrict__ logits, const int* __restrict__ y,
            const int* __restrict__ mask, const float2* __restrict__ xzw,
            const int* __restrict__ widx, const float* __restrict__ cw,
            float* __restrict__ ce_part,
            unsigned* __restrict__ g_seg_u32, unsigned* __restrict__ part,
            unsigned* __restrict__ keys, unsigned* __restrict__ gh1,
            int use_part, int use_keys, int n)
{
    __shared__ unsigned s_seg[SEGW];       // 48 KB packed
    __shared__ unsigned s_h1[1024];        // 4 KB u16-pair histogram
    __shared__ float s_redf[2 * NWAVES];
    __shared__ unsigned s_redu[3 * NWAVES];
    for (int j = threadIdx.x; j < SEGW; j += BLOCK_MAIN) s_seg[j] = 0u;
    for (int j = threadIdx.x; j < 1024; j += BLOCK_MAIN) s_h1[j] = 0u;
    __syncthreads();

    const float cw0 = cw[0], cw1 = cw[1];
    float num = 0.0f, den = 0.0f;
    unsigned nv = 0u, nm = 0u, zc = 0u;

    const int nth = gridDim.x * BLOCK_MAIN;
    const int gtid = blockIdx.x * BLOCK_MAIN + threadIdx.x;
    const int nq = n >> 2;

    const float4* lg4 = (const float4*)logits;
    const int4* y4p = (const int4*)y;
    const int4* m4p = (const int4*)mask;
    const int4* w4p = (const int4*)widx;

    for (int q = gtid; q < nq; q += nth) {
        float4 lgA = lg4[2 * q], lgB = lg4[2 * q + 1];
        int4 y4 = y4p[q], m4 = m4p[q], w4 = w4p[q];
        float2 z0 = xzw[8 * q + 1], z1 = xzw[8 * q + 3];
        float2 z2 = xzw[8 * q + 5], z3 = xzw[8 * q + 7];

        uint4 kq;
        process_elem(lgA.x, lgA.y, y4.x, m4.x, z0.x, z0.y, w4.x,
                     cw0, cw1, &kq.x, num, den, nv, nm, zc, s_seg, s_h1);
        process_elem(lgA.z, lgA.w, y4.y, m4.y, z1.x, z1.y, w4.y,
                     cw0, cw1, &kq.y, num, den, nv, nm, zc, s_seg, s_h1);
        process_elem(lgB.x, lgB.y, y4.z, m4.z, z2.x, z2.y, w4.z,
                     cw0, cw1, &kq.z, num, den, nv, nm, zc, s_seg, s_h1);
        process_elem(lgB.z, lgB.w, y4.w, m4.w, z3.x, z3.y, w4.w,
                     cw0, cw1, &kq.w, num, den, nv, nm, zc, s_seg, s_h1);
        if (use_keys) ((uint4*)keys)[q] = kq;
    }
    for (int i = (nq << 2) + gtid; i < n; i += nth) {   // tail (n%4)
        float2 lg = logits[i];
        float2 zz = xzw[2 * i + 1];
        unsigned k;
        process_elem(lg.x, lg.y, y[i], mask[i], zz.x, zz.y, widx[i],
                     cw0, cw1, &k, num, den, nv, nm, zc, s_seg, s_h1);
        if (use_keys) keys[i] = k;
    }

    // wave(64) shuffle reduce -> LDS -> one private-slot store per block
    for (int off = 32; off > 0; off >>= 1) {
        num += __shfl_down(num, off);
        den += __shfl_down(den, off);
        nv  += __shfl_down(nv, off);
        nm  += __shfl_down(nm, off);
        zc  += __shfl_down(zc, off);
    }
    const int wid = threadIdx.x >> 6;
    if ((threadIdx.x & 63) == 0) {
        s_redf[wid] = num; s_redf[NWAVES + wid] = den;
        s_redu[wid] = nv; s_redu[NWAVES + wid] = nm; s_redu[2 * NWAVES + wid] = zc;
    }
    __syncthreads();
    if (threadIdx.x == 0) {
        float tn = 0.0f, td = 0.0f;
        unsigned ta = 0u, tb = 0u, tc = 0u;
        for (int w = 0; w < NWAVES; ++w) {
            tn += s_redf[w]; td += s_redf[NWAVES + w];
            ta += s_redu[w]; tb += s_redu[NWAVES + w]; tc += s_redu[2 * NWAVES + w];
        }
        float* cp = ce_part + blockIdx.x * 8;
        cp[0] = tn; cp[1] = td;
        ((unsigned*)cp)[2] = ta; ((unsigned*)cp)[3] = tb; ((unsigned*)cp)[4] = tc;
    }

    if (use_part) {
        uint4* dst = (uint4*)(part + (size_t)blockIdx.x * SEGW);
        const uint4* src = (const uint4*)s_seg;
        for (int j = threadIdx.x; j < SEGW / 4; j += BLOCK_MAIN) dst[j] = src[j];
    } else {
        for (int j = threadIdx.x; j < SEGW; j += BLOCK_MAIN) {
            unsigned v = s_seg[j];
            if (v) {
                unsigned wi = (unsigned)j / 3u, t = (unsigned)j % 3u;
                if (t == 0u) {
                    atomicAdd(&g_seg_u32[(wi << 2)], v >> 24);
                    atomicAdd(&g_seg_u32[(wi << 2) + 1], v & 0xFFFFFFu);
                } else {
                    atomicAdd(&g_seg_u32[(wi << 2) + 1 + t], v);
                }
            }
        }
    }
    for (int j = threadIdx.x; j < 1024; j += BLOCK_MAIN) {
        unsigned v = s_h1[j];
        unsigned lo = v & 0xFFFFu, hi = v >> 16;
        if (lo) atomicAdd(&gh1[2 * j], lo);
        if (hi) atomicAdd(&gh1[2 * j + 1], hi);
    }
}

// ---------------- generic block-wide scan + rank search ----------------
__device__ void scan_search_g(const unsigned* __restrict__ gh, int NB, unsigned rank,
                              unsigned zadd, unsigned* sv, unsigned* wsb,
                              unsigned* ret)
{
    const int tid = threadIdx.x;
    const int B = blockDim.x;
    for (int j = tid; j < NB; j += B) sv[j] = gh[j] + ((j == 0) ? zadd : 0u);
    __syncthreads();
    const int E = NB / B;
    const int base = tid * E;
    unsigned loc = 0u;
    for (int e = 0; e < E; ++e) loc += sv[base + e];
    unsigned inc = loc;
    const int lane = tid & 63;
    for (int off = 1; off < 64; off <<= 1) {
        unsigned u = __shfl_up(inc, off);
        if (lane >= off) inc += u;
    }
    const int wid = tid >> 6;
    const int nw = B >> 6;
    if (lane == 63) wsb[wid] = inc;
    __syncthreads();
    if (tid == 0) {
        unsigned run = 0u;
        for (int w = 0; w < nw; ++w) { unsigned t = wsb[w]; wsb[w] = run; run += t; }
    }
    __syncthreads();
    unsigned c = wsb[wid] + (inc - loc);
    for (int e = 0; e < E; ++e) {
        unsigned hv = sv[base + e];
        if (rank >= c && rank < c + hv) { ret[0] = (unsigned)(base + e); ret[1] = rank - c; }
        c += hv;
    }
    __syncthreads();
}

// ---------------- fused post: blocks 0-95 unpack+reduce partials; block 96 CE+scan1 ----------------
extern "C" __global__ __launch_bounds__(512)
void k_post(const unsigned* __restrict__ part, unsigned* __restrict__ g_seg_u32,
            const float* __restrict__ ce_part, double* __restrict__ ws_d,
            unsigned* __restrict__ ws_u, float* __restrict__ ws_f,
            const unsigned* __restrict__ gh1, int use_part, int grid)
{
    if (blockIdx.x < 96) {
        if (!use_part) return;
        const int c = blockIdx.x / 24;                 // chunk 0..3
        const int bin = (blockIdx.x % 24) * 512 + threadIdx.x;   // 0..12287
        const int per = grid >> 2;
        const unsigned* p = part + (size_t)c * per * SEGW + bin;
        const unsigned wi = (unsigned)bin / 3u, t = (unsigned)bin % 3u;
        if (t == 0u) {
            unsigned cnt = 0u, ps = 0u;
            for (int b = 0; b < per; ++b) {
                unsigned w = p[(size_t)b * SEGW];
                cnt += w >> 24; ps += w & 0xFFFFFFu;
            }
            if (cnt) atomicAdd(&g_seg_u32[wi << 2], cnt);
            if (ps)  atomicAdd(&g_seg_u32[(wi << 2) + 1], ps);
        } else {
            unsigned s = 0u;
            for (int b = 0; b < per; ++b) s += p[(size_t)b * SEGW];
            if (s) atomicAdd(&g_seg_u32[(wi << 2) + 1 + t], s);
        }
        return;
    }

    // ---- block 96: CE finalize + level-1 scan ----
    __shared__ unsigned sv[2048];
    __shared__ unsigned wsb[16];
    __shared__ unsigned ret[2];
    __shared__ double sd[2 * 8];
    __shared__ unsigned su[3 * 8];
    __shared__ unsigned bc[4];
    __shared__ float bf[1];

    const int tid = threadIdx.x;
    double n_ = 0.0, d_ = 0.0;
    unsigned a = 0u, b = 0u, c = 0u;
    for (int s0 = tid; s0 < grid; s0 += 512) {
        const float* cp = ce_part + s0 * 8;
        n_ += (double)cp[0];
        d_ += (double)cp[1];
        a += ((const unsigned*)cp)[2];
        b += ((const unsigned*)cp)[3];
        c += ((const unsigned*)cp)[4];
    }
    for (int off = 32; off > 0; off >>= 1) {
        n_ += __shfl_down(n_, off);
        d_ += __shfl_down(d_, off);
        a  += __shfl_down(a, off);
        b  += __shfl_down(b, off);
        c  += __shfl_down(c, off);
    }
    const int wid = tid >> 6;
    if ((tid & 63) == 0) { sd[wid] = n_; sd[8 + wid] = d_;
                           su[wid] = a; su[8 + wid] = b; su[16 + wid] = c; }
    __syncthreads();
    if (tid == 0) {
        double tn = 0.0, td = 0.0;
        unsigned ta = 0u, tb = 0u, tc = 0u;
        for (int w = 0; w < 8; ++w) {
            tn += sd[w]; td += sd[8 + w];
            ta += su[w]; tb += su[8 + w]; tc += su[16 + w];
        }
        ws_d[0] = tn; ws_d[1] = td;
        ws_u[4] = ta; ws_u[5] = tb;
        float nf = (float)((int)ta - 1);
        float pos = fmaxf(0.75f * nf, 0.0f);
        float lo = floorf(pos);
        bf[0] = pos - lo;
        bc[0] = tc;
        bc[2] = (unsigned)lo;
        bc[3] = (unsigned)ceilf(pos);
    }
    __syncthreads();
    const unsigned zadd = bc[0];
    const unsigned r0 = bc[2], r1 = bc[3];
    if (tid == 0) ws_f[7] = bf[0];

    scan_search_g(gh1, 2048, r0, zadd, sv, wsb, ret);
    if (tid == 0) { ws_u[8] = ret[0]; ws_u[10] = ret[1]; }
    scan_search_g(gh1, 2048, r1, zadd, sv, wsb, ret);
    if (tid == 0) { ws_u[9] = ret[0]; ws_u[11] = ret[1]; }
}

// ---------------- histogram passes 2 and 3 ----------------
__device__ __forceinline__ void h2_one(unsigned key, unsigned p0, unsigned p1,
                                       unsigned* h)
{
    unsigned top = key >> 21;
    unsigned sub = (key >> 10) & 2047u;
    if (top == p0) atomicAdd(&h[sub], 1u);
    if (top == p1) atomicAdd(&h[2048 + sub], 1u);
}

extern "C" __global__ __launch_bounds__(256)
void k_hist2(const unsigned* __restrict__ keys, const float2* __restrict__ xzw,
             const int* __restrict__ mask, const int* __restrict__ widx,
             int use_keys, int n, const unsigned* __restrict__ ws_u,
             unsigned* __restrict__ gh)
{
    __shared__ unsigned h[2 * 2048];
    for (int j = threadIdx.x; j < 2 * 2048; j += 256) h[j] = 0u;
    __syncthreads();
    const unsigned p0 = ws_u[8], p1 = ws_u[9];
    const int nthr = gridDim.x * blockDim.x;
    const int gtid = blockIdx.x * blockDim.x + threadIdx.x;
    const int nq = n >> 2;
    if (use_keys) {
        const uint4* k4 = (const uint4*)keys;
        int base = gtid;
        for (; base + 3 * nthr < nq; base += 4 * nthr) {
            uint4 a = k4[base], b = k4[base + nthr];
            uint4 c = k4[base + 2 * nthr], d = k4[base + 3 * nthr];
            h2_one(a.x, p0, p1, h); h2_one(a.y, p0, p1, h);
            h2_one(a.z, p0, p1, h); h2_one(a.w, p0, p1, h);
            h2_one(b.x, p0, p1, h); h2_one(b.y, p0, p1, h);
            h2_one(b.z, p0, p1, h); h2_one(b.w, p0, p1, h);
            h2_one(c.x, p0, p1, h); h2_one(c.y, p0, p1, h);
            h2_one(c.z, p0, p1, h); h2_one(c.w, p0, p1, h);
            h2_one(d.x, p0, p1, h); h2_one(d.y, p0, p1, h);
            h2_one(d.z, p0, p1, h); h2_one(d.w, p0, p1, h);
        }
        for (; base < nq; base += nthr) {
            uint4 a = k4[base];
            h2_one(a.x, p0, p1, h); h2_one(a.y, p0, p1, h);
            h2_one(a.z, p0, p1, h); h2_one(a.w, p0, p1, h);
        }
        for (int i = (nq << 2) + gtid; i < n; i += nthr)
            h2_one(keys[i], p0, p1, h);
    } else {
        for (int i = gtid; i < n; i += nthr)
            h2_one(make_key_raw(xzw, mask, widx, i), p0, p1, h);
    }
    __syncthreads();
    for (int j = threadIdx.x; j < 2 * 2048; j += 256)
        if (h[j]) atomicAdd(&gh[j], h[j]);
}

extern "C" __global__ __launch_bounds__(256)
void k_scan2(unsigned* __restrict__ ws_u, const unsigned* __restrict__ gh)
{
    __shared__ unsigned sv[2048];
    __shared__ unsigned wsb[16];
    __shared__ unsigned ret[2];
    unsigned p0 = ws_u[8], p1 = ws_u[9];
    unsigned r0 = ws_u[10], r1 = ws_u[11];
    scan_search_g(gh, 2048, r0, 0u, sv, wsb, ret);
    if (threadIdx.x == 0) { ws_u[8] = (p0 << 11) | ret[0]; ws_u[10] = ret[1]; }
    scan_search_g(gh + 2048, 2048, r1, 0u, sv, wsb, ret);
    if (threadIdx.x == 0) { ws_u[9] = (p1 << 11) | ret[0]; ws_u[11] = ret[1]; }
}

__device__ __forceinline__ void h3_one(unsigned key, unsigned p0, unsigned p1,
                                       unsigned* h)
{
    unsigned top = key >> 10;
    unsigned sub = key & 1023u;
    if (top == p0) atomicAdd(&h[sub], 1u);
    if (top == p1) atomicAdd(&h[1024 + sub], 1u);
}

extern "C" __global__ __launch_bounds__(256)
void k_hist3(const unsigned* __restrict__ keys, const float2* __restrict__ xzw,
             const int* __restrict__ mask, const int* __restrict__ widx,
             int use_keys, int n, const unsigned* __restrict__ ws_u,
             unsigned* __restrict__ gh)
{
    __shared__ unsigned h[2 * 1024];
    for (int j = threadIdx.x; j < 2 * 1024; j += 256) h[j] = 0u;
    __syncthreads();
    const unsigned p0 = ws_u[8], p1 = ws_u[9];
    const int nthr = gridDim.x * blockDim.x;
    const int gtid = blockIdx.x * blockDim.x + threadIdx.x;
    const int nq = n >> 2;
    if (use_keys) {
        const uint4* k4 = (const uint4*)keys;
        int base = gtid;
        for (; base + 3 * nthr < nq; base += 4 * nthr) {
            uint4 a = k4[base], b = k4[base + nthr];
            uint4 c = k4[base + 2 * nthr], d = k4[base + 3 * nthr];
            h3_one(a.x, p0, p1, h); h3_one(a.y, p0, p1, h);
            h3_one(a.z, p0, p1, h); h3_one(a.w, p0, p1, h);
            h3_one(b.x, p0, p1, h); h3_one(b.y, p0, p1, h);
            h3_one(b.z, p0, p1, h); h3_one(b.w, p0, p1, h);
            h3_one(c.x, p0, p1, h); h3_one(c.y, p0, p1, h);
            h3_one(c.z, p0, p1, h); h3_one(c.w, p0, p1, h);
            h3_one(d.x, p0, p1, h); h3_one(d.y, p0, p1, h);
            h3_one(d.z, p0, p1, h); h3_one(d.w, p0, p1, h);
        }
        for (; base < nq; base += nthr) {
            uint4 a = k4[base];
            h3_one(a.x, p0, p1, h); h3_one(a.y, p0, p1, h);
            h3_one(a.z, p0, p1, h); h3_one(a.w, p0, p1, h);
        }
        for (int i = (nq << 2) + gtid; i < n; i += nthr)
            h3_one(keys[i], p0, p1, h);
    } else {
        for (int i = gtid; i < n; i += nthr)
            h3_one(make_key_raw(xzw, mask, widx, i), p0, p1, h);
    }
    __syncthreads();
    for (int j = threadIdx.x; j < 2 * 1024; j += 256)
        if (h[j]) atomicAdd(&gh[j], h[j]);
}

// ---------------- finalize: fused scan3 + window loss ----------------
extern "C" __global__ __launch_bounds__(1024)
void k_final(const unsigned* __restrict__ g_seg_u32, const double* __restrict__ ws_d,
             const float* __restrict__ ws_f, const unsigned* __restrict__ ws_u,
             const unsigned* __restrict__ gh3, float* __restrict__ out)
{
    __shared__ unsigned sv[1024];
    __shared__ unsigned wsb[16];
    __shared__ unsigned ret[2];
    __shared__ double red[48];

    const unsigned p0 = ws_u[8], p1 = ws_u[9];
    const unsigned r0 = ws_u[10], r1 = ws_u[11];
    scan_search_g(gh3, 1024, r0, 0u, sv, wsb, ret);
    const float v0 = __uint_as_float((p0 << 10) | ret[0]);
    scan_search_g(gh3 + 1024, 1024, r1, 0u, sv, wsb, ret);
    const float v1 = __uint_as_float((p1 << 10) | ret[0]);

    const int nvalid = (int)ws_u[4];
    const float frac = ws_f[7];
    const float qf = v0 * (1.0f - frac) + v1 * frac;
    const double ref = (double)((nvalid > 0) ? fmaxf(qf, EPSF) : 1.0f);

    const uint4* gs4 = (const uint4*)g_seg_u32;
    double ninc = 0.0, fsum = 0.0, lsum = 0.0;
    for (int w = threadIdx.x; w < NWIN; w += blockDim.x) {
        uint4 v = gs4[w];
        double c   = (double)v.x;
        double sp  = (double)v.y * INV_P;
        double ar  = (double)v.z * INV_R;
        double spd = (double)v.w * INV_R;
        double inc = (c >= 2.0 && sp >= 1e-6) ? 1.0 : 0.0;
        double dmean = spd / (sp + 1e-6);
        double rr = ar / (1000.0 + 1e-6);
        double bu = fmax(rr - 1.0, 0.0);
        double flow = bu * bu;
        double rho = fmin(fmax(rr, 0.0), 0.99);
        double dth = 1.0 / (1.0 - rho + 1e-6);
        double lat = fmax(dth - dmean / ref, 0.0);
        ninc += inc; fsum += flow * inc; lsum += lat * inc;
    }
    for (int off = 32; off > 0; off >>= 1) {
        ninc += __shfl_down(ninc, off);
        fsum += __shfl_down(fsum, off);
        lsum += __shfl_down(lsum, off);
    }
    int wid = threadIdx.x >> 6, lane = threadIdx.x & 63;
    if (lane == 0) { red[wid] = ninc; red[16 + wid] = fsum; red[32 + wid] = lsum; }
    __syncthreads();
    if (threadIdx.x == 0) {
        double n_i = 0.0, f_s = 0.0, l_s = 0.0;
        int nw = (int)blockDim.x >> 6;
        for (int w = 0; w < nw; ++w) { n_i += red[w]; f_s += red[16 + w]; l_s += red[32 + w]; }
        double safe = fmax(n_i, 1.0);
        double l_flow = (n_i > 0.0) ? f_s / safe : 0.0;
        double l_lat  = (n_i > 0.0) ? l_s / safe : 0.0;
        double den = ws_d[1];
        double l_data = ws_d[0] / fmax(den, 1e-12);
        bool any = ws_u[5] > 0u;
        if (!any) { l_data = 0.0; l_flow = 0.0; l_lat = 0.0; }
        out[0] = (float)(l_data + 0.1 * l_flow + 0.1 * l_lat);
        out[1] = (float)l_data;
        out[2] = (float)l_flow;
        out[3] = (float)l_lat;
    }
}

extern "C" void kernel_launch(void* const* d_in, const int* in_sizes, int n_in,
                              void* d_out, int out_size, void* d_ws, size_t ws_size,
                              hipStream_t stream)
{
    const float2* logits = (const float2*)d_in[0];
    const int* y = (const int*)d_in[1];
    const int* mask = (const int*)d_in[2];       // bool delivered as int32
    const float2* xzw = (const float2*)d_in[3];  // x_raw viewed as float2 pairs
    const int* widx = (const int*)d_in[4];
    const float* cw = (const float*)d_in[5];
    float* out = (float*)d_out;
    const int n = in_sizes[1];   // N from y

    unsigned char* ws8 = (unsigned char*)d_ws;
    double* ws_d = (double*)ws8;
    float* ws_f = (float*)ws8;
    unsigned* ws_u = (unsigned*)ws8;
    unsigned* g_seg_u32 = (unsigned*)(ws8 + OFF_SEGU);
    unsigned* g_h1 = (unsigned*)(ws8 + OFF_H1);
    unsigned* g_h2 = (unsigned*)(ws8 + OFF_H2);
    unsigned* g_h3 = (unsigned*)(ws8 + OFF_H3);
    float* ce_part = (float*)(ws8 + OFF_CEP);

    const size_t keys_bytes = (size_t)n * 4u;
    // pick the largest grid whose part buffer fits (3 blocks/CU target)
    int grid = 768;
    int use_part = 0, use_keys = 0;
    size_t part_bytes = 0;
    for (;;) {
        part_bytes = (size_t)grid * SEGW * 4u;
        if (ws_size >= OFF_PART + part_bytes + keys_bytes) { use_part = 1; use_keys = 1; break; }
        if (ws_size >= OFF_PART + part_bytes) { use_part = 1; break; }
        if (grid == 768) { grid = 512; continue; }
        if (ws_size >= OFF_PART + keys_bytes) use_keys = 1;
        break;
    }
    unsigned* part = (unsigned*)(ws8 + OFF_PART);
    unsigned* keys = (unsigned*)(ws8 + OFF_PART + (use_part ? part_bytes : 0));

    hipMemsetAsync(d_ws, 0, OFF_PART, stream);   // header + g_seg_u32 + hists + cep

    k_main<<<grid, BLOCK_MAIN, 0, stream>>>(logits, y, mask, xzw, widx, cw,
                                            ce_part, g_seg_u32, part, keys,
                                            g_h1, use_part, use_keys, n);
    k_post<<<97, 512, 0, stream>>>(part, g_seg_u32, ce_part, ws_d, ws_u, ws_f,
                                   g_h1, use_part, grid);
    k_hist2<<<1024, 256, 0, stream>>>(keys, xzw, mask, widx, use_keys, n, ws_u, g_h2);
    k_scan2<<<1, 256, 0, stream>>>(ws_u, g_h2);
    k_hist3<<<1024, 256, 0, stream>>>(keys, xzw, mask, widx, use_keys, n, ws_u, g_h3);
    k_final<<<1, 1024, 0, stream>>>(g_seg_u32, ws_d, ws_f, ws_u, g_h3, out);
}

// Round 14
// 115.076 us; speedup vs baseline: 1.2952x; 1.2952x over previous
//
#include <hip/hip_runtime.h>

#define NWIN 4096
#define EPSF 1e-6f
#define GRID_MAIN 512
#define BLOCK_MAIN 512
#define NWAVES (BLOCK_MAIN / 64)
#define SEGW (3 * NWIN)          // packed: [wi*3] = cnt<<24|p*2^16, [+1] rate, [+2] pd
#define CHUNK 384                // elements per staged chunk
#define CWORDS 2688              // staged u32 words: lg 768 | y 384 | m 384 | w 384 | zw 768
#define NGROUP 42                // CWORDS / 64

// fixed-point scales
#define SCALE_P   65536.0f       // 2^16  sum_p (low 24 bits of packed word0)
#define SCALE_R   131072.0f      // 2^17  agg_rate / sum_pd
#define INV_P     (1.0/65536.0)
#define INV_R     (1.0/131072.0)

// ---------------- workspace layout (bytes) ----------------
//  byte 0: double ce_num   byte 8: double ce_den
//  byte 16: u32 n_valid(u[4]) byte 20: u32 n_mask(u[5])
//  byte 24: f32 ref_dobs(f[6]) byte 28: f32 frac(f[7])
//  byte 32,36: u32 prefixes(u[8],u[9])  byte 40,44: u32 ranks(u[10],u[11])
#define OFF_SEGU  256            // u32 g_seg_u32[16384]  [wi*4+c] unpacked
#define OFF_H1    65792          // u32[2048]
#define OFF_H2    73984          // u32[2*2048]
#define OFF_H3    90368          // u32[2*1024]
#define OFF_CEP   98560          // float ce_part[512*8] (16 KB)
#define OFF_PART  131072         // part (512 x 48KB = 25.2MB) | keys

__device__ __forceinline__ unsigned make_key_raw(const float2* __restrict__ xzw,
                                                 const int* __restrict__ mask,
                                                 const int* __restrict__ widx, int i)
{
    int wi = widx[i];
    int m = mask[i];
    if (wi < 0 || !m) return 0x7F800000u;
    float d = fmaxf(xzw[2 * i + 1].x, 0.0f);
    unsigned k = __float_as_uint(d);
    return (k == 0x80000000u) ? 0u : k;
}

// ---------------- per-element fused work (branchless, packed LDS) ----------------
__device__ __forceinline__ void process_elem(
    float lgx, float lgy, int yi, int mi, float xz, float xw, int wi,
    float cw0, float cw1, unsigned* keyOut,
    float& num, float& den, unsigned& nv, unsigned& nm, unsigned& zc,
    unsigned* s_seg, unsigned* s_h1)
{
    float d = lgx - lgy;
    float ad = fabsf(d);
    float t = __expf(-ad);
    float inv1t = 1.0f / (1.0f + t);
    float l1p = __logf(1.0f + t);
    float s = yi ? d : -d;
    float nll = fmaxf(s, 0.0f) + l1p;
    float maskf = mi ? 1.0f : 0.0f;
    float wy = (yi ? cw1 : cw0) * maskf;
    nm += (mi != 0);
    num += wy * nll;
    den += wy;

    bool vq = (wi >= 0) && mi;
    float dob = fmaxf(xz, 0.0f);
    unsigned kraw = __float_as_uint(dob);
    kraw = (kraw == 0x80000000u) ? 0u : kraw;
    unsigned key = vq ? kraw : 0x7F800000u;
    *keyOut = key;
    nv += vq;
    zc += (key == 0u);

    // hist1: u16-packed pairs; zeros add 0
    unsigned hb = key >> 21;
    atomicAdd(&s_h1[hb >> 1], (key != 0u) ? (1u << ((hb & 1u) << 4)) : 0u);

    // segment sums, packed word0 = cnt<<24 | p*2^16 (invalid adds 0 to window 0)
    bool sv = vq && ((unsigned)wi < NWIN);
    unsigned b = sv ? ((unsigned)wi * 3u) : 0u;
    float p = ((d > 0.0f) ? t : 1.0f) * inv1t;
    float rate = fmaxf(xw, 0.0f);
    unsigned a0 = sv ? ((1u << 24) | (unsigned)(p * SCALE_P + 0.5f)) : 0u;
    unsigned a1 = sv ? (unsigned)(p * rate * SCALE_R + 0.5f) : 0u;
    unsigned a2 = sv ? (unsigned)(p * dob * SCALE_R + 0.5f) : 0u;
    atomicAdd(&s_seg[b], a0);
    atomicAdd(&s_seg[b + 1], a1);
    atomicAdd(&s_seg[b + 2], a2);
}

// ---------------- DMA one chunk into LDS (fire-and-forget, no VGPR cost) ----------------
__device__ __forceinline__ void issue_chunk(int c, unsigned* dst,
                                            const unsigned* __restrict__ lgw,
                                            const unsigned* __restrict__ yw,
                                            const unsigned* __restrict__ mw,
                                            const unsigned* __restrict__ ww,
                                            const unsigned* __restrict__ xrw,
                                            int wid, int lane)
{
    // group boundaries align with streams: 0-11 lg, 12-17 y, 18-23 m, 24-29 w, 30-41 zw
    for (int g = wid; g < NGROUP; g += NWAVES) {
        const int wb = g << 6;            // wave-uniform word base in chunk
        const int w = wb + lane;
        const unsigned* src;
        if (wb < 768)        src = lgw + (size_t)c * 768 + w;
        else if (wb < 1152)  src = yw + (size_t)c * 384 + (w - 768);
        else if (wb < 1536)  src = mw + (size_t)c * 384 + (w - 1152);
        else if (wb < 1920)  src = ww + (size_t)c * 384 + (w - 1536);
        else {
            int j = w - 1920;             // zw: 2 words per elem, strided in x_raw
            src = xrw + (size_t)c * 1536 + ((unsigned)(j >> 1) << 2) + 2 + (j & 1);
        }
        __builtin_amdgcn_global_load_lds(
            (const __attribute__((address_space(1))) void*)src,
            (__attribute__((address_space(3))) void*)(dst + wb), 4, 0, 0);
    }
}

// ---------------- main fused pass (gl_lds staged, double-buffered) ----------------
extern "C" __global__ __launch_bounds__(BLOCK_MAIN)
void k_main(const float2* __restrict__ logits, const int* __restrict__ y,
            const int* __restrict__ mask, const float2* __restrict__ xzw,
            const int* __restrict__ widx, const float* __restrict__ cw,
            float* __restrict__ ce_part,
            unsigned* __restrict__ g_seg_u32, unsigned* __restrict__ part,
            unsigned* __restrict__ keys, unsigned* __restrict__ gh1,
            int use_part, int use_keys, int n)
{
    __shared__ unsigned s_seg[SEGW];       // 48 KB packed
    __shared__ unsigned s_h1[1024];        // 4 KB u16-pair histogram
    __shared__ unsigned stg[2][CWORDS];    // 2 x 10.5 KB staging
    __shared__ float s_redf[2 * NWAVES];
    __shared__ unsigned s_redu[3 * NWAVES];
    for (int j = threadIdx.x; j < SEGW; j += BLOCK_MAIN) s_seg[j] = 0u;
    for (int j = threadIdx.x; j < 1024; j += BLOCK_MAIN) s_h1[j] = 0u;
    __syncthreads();

    const float cw0 = cw[0], cw1 = cw[1];
    float num = 0.0f, den = 0.0f;
    unsigned nv = 0u, nm = 0u, zc = 0u;

    const int tid = threadIdx.x;
    const int lane = tid & 63;
    const int wid = tid >> 6;
    const int nchunks = n / CHUNK;

    const unsigned* lgw = (const unsigned*)logits;
    const unsigned* yw = (const unsigned*)y;
    const unsigned* mw = (const unsigned*)mask;
    const unsigned* ww = (const unsigned*)widx;
    const unsigned* xrw = (const unsigned*)xzw;

    int c = blockIdx.x;
    int buf = 0;
    if (c < nchunks) {
        issue_chunk(c, stg[0], lgw, yw, mw, ww, xrw, wid, lane);
        asm volatile("s_waitcnt vmcnt(0)" ::: "memory");
        __syncthreads();
        while (c < nchunks) {
            int cn = c + gridDim.x;
            if (cn < nchunks)
                issue_chunk(cn, stg[buf ^ 1], lgw, yw, mw, ww, xrw, wid, lane);
            if (tid < CHUNK) {
                const unsigned* st = stg[buf];
                float lgx = __uint_as_float(st[2 * tid]);
                float lgy = __uint_as_float(st[2 * tid + 1]);
                int yi = (int)st[768 + tid];
                int mi = (int)st[1152 + tid];
                int wi = (int)st[1536 + tid];
                float xz = __uint_as_float(st[1920 + 2 * tid]);
                float xw = __uint_as_float(st[1921 + 2 * tid]);
                unsigned key;
                process_elem(lgx, lgy, yi, mi, xz, xw, wi, cw0, cw1, &key,
                             num, den, nv, nm, zc, s_seg, s_h1);
                if (use_keys) keys[(size_t)c * CHUNK + tid] = key;
            }
            asm volatile("s_waitcnt vmcnt(0)" ::: "memory");
            __syncthreads();
            buf ^= 1;
            c = cn;
        }
    }
    // scalar tail: elements beyond nchunks*CHUNK
    for (int i = nchunks * CHUNK + blockIdx.x * BLOCK_MAIN + tid; i < n;
         i += gridDim.x * BLOCK_MAIN) {
        float2 lg = logits[i];
        float2 zz = xzw[2 * i + 1];
        unsigned key;
        process_elem(lg.x, lg.y, y[i], mask[i], zz.x, zz.y, widx[i],
                     cw0, cw1, &key, num, den, nv, nm, zc, s_seg, s_h1);
        if (use_keys) keys[i] = key;
    }

    // wave(64) shuffle reduce -> LDS -> one private-slot store per block
    for (int off = 32; off > 0; off >>= 1) {
        num += __shfl_down(num, off);
        den += __shfl_down(den, off);
        nv  += __shfl_down(nv, off);
        nm  += __shfl_down(nm, off);
        zc  += __shfl_down(zc, off);
    }
    if (lane == 0) {
        s_redf[wid] = num; s_redf[NWAVES + wid] = den;
        s_redu[wid] = nv; s_redu[NWAVES + wid] = nm; s_redu[2 * NWAVES + wid] = zc;
    }
    __syncthreads();
    if (tid == 0) {
        float tn = 0.0f, td = 0.0f;
        unsigned ta = 0u, tb = 0u, tc = 0u;
        for (int w = 0; w < NWAVES; ++w) {
            tn += s_redf[w]; td += s_redf[NWAVES + w];
            ta += s_redu[w]; tb += s_redu[NWAVES + w]; tc += s_redu[2 * NWAVES + w];
        }
        float* cp = ce_part + blockIdx.x * 8;
        cp[0] = tn; cp[1] = td;
        ((unsigned*)cp)[2] = ta; ((unsigned*)cp)[3] = tb; ((unsigned*)cp)[4] = tc;
    }

    if (use_part) {
        uint4* dst = (uint4*)(part + (size_t)blockIdx.x * SEGW);
        const uint4* src = (const uint4*)s_seg;
        for (int j = tid; j < SEGW / 4; j += BLOCK_MAIN) dst[j] = src[j];
    } else {
        for (int j = tid; j < SEGW; j += BLOCK_MAIN) {
            unsigned v = s_seg[j];
            if (v) {
                unsigned wi = (unsigned)j / 3u, t = (unsigned)j % 3u;
                if (t == 0u) {
                    atomicAdd(&g_seg_u32[(wi << 2)], v >> 24);
                    atomicAdd(&g_seg_u32[(wi << 2) + 1], v & 0xFFFFFFu);
                } else {
                    atomicAdd(&g_seg_u32[(wi << 2) + 1 + t], v);
                }
            }
        }
    }
    for (int j = tid; j < 1024; j += BLOCK_MAIN) {
        unsigned v = s_h1[j];
        unsigned lo = v & 0xFFFFu, hi = v >> 16;
        if (lo) atomicAdd(&gh1[2 * j], lo);
        if (hi) atomicAdd(&gh1[2 * j + 1], hi);
    }
}

// ---------------- generic block-wide scan + rank search ----------------
__device__ void scan_search_g(const unsigned* __restrict__ gh, int NB, unsigned rank,
                              unsigned zadd, unsigned* sv, unsigned* wsb,
                              unsigned* ret)
{
    const int tid = threadIdx.x;
    const int B = blockDim.x;
    for (int j = tid; j < NB; j += B) sv[j] = gh[j] + ((j == 0) ? zadd : 0u);
    __syncthreads();
    const int E = NB / B;
    const int base = tid * E;
    unsigned loc = 0u;
    for (int e = 0; e < E; ++e) loc += sv[base + e];
    unsigned inc = loc;
    const int lane = tid & 63;
    for (int off = 1; off < 64; off <<= 1) {
        unsigned u = __shfl_up(inc, off);
        if (lane >= off) inc += u;
    }
    const int wid = tid >> 6;
    const int nw = B >> 6;
    if (lane == 63) wsb[wid] = inc;
    __syncthreads();
    if (tid == 0) {
        unsigned run = 0u;
        for (int w = 0; w < nw; ++w) { unsigned t = wsb[w]; wsb[w] = run; run += t; }
    }
    __syncthreads();
    unsigned c = wsb[wid] + (inc - loc);
    for (int e = 0; e < E; ++e) {
        unsigned hv = sv[base + e];
        if (rank >= c && rank < c + hv) { ret[0] = (unsigned)(base + e); ret[1] = rank - c; }
        c += hv;
    }
    __syncthreads();
}

// ---------------- fused post: blocks 0-95 unpack+reduce partials; block 96 CE+scan1 ----------------
extern "C" __global__ __launch_bounds__(512)
void k_post(const unsigned* __restrict__ part, unsigned* __restrict__ g_seg_u32,
            const float* __restrict__ ce_part, double* __restrict__ ws_d,
            unsigned* __restrict__ ws_u, float* __restrict__ ws_f,
            const unsigned* __restrict__ gh1, int use_part)
{
    if (blockIdx.x < 96) {
        if (!use_part) return;
        const int c = blockIdx.x / 24;                            // chunk 0..3
        const int bin = (blockIdx.x % 24) * 512 + threadIdx.x;    // 0..12287
        const unsigned* p = part + (size_t)c * 128 * SEGW + bin;
        const unsigned wi = (unsigned)bin / 3u, t = (unsigned)bin % 3u;
        if (t == 0u) {
            unsigned cnt = 0u, ps = 0u;
#pragma unroll 8
            for (int b = 0; b < 128; ++b) {
                unsigned w = p[(size_t)b * SEGW];
                cnt += w >> 24; ps += w & 0xFFFFFFu;
            }
            if (cnt) atomicAdd(&g_seg_u32[wi << 2], cnt);
            if (ps)  atomicAdd(&g_seg_u32[(wi << 2) + 1], ps);
        } else {
            unsigned s = 0u;
#pragma unroll 8
            for (int b = 0; b < 128; ++b) s += p[(size_t)b * SEGW];
            if (s) atomicAdd(&g_seg_u32[(wi << 2) + 1 + t], s);
        }
        return;
    }

    // ---- block 96: CE finalize + level-1 scan ----
    __shared__ unsigned sv[2048];
    __shared__ unsigned wsb[16];
    __shared__ unsigned ret[2];
    __shared__ double sd[2 * 8];
    __shared__ unsigned su[3 * 8];
    __shared__ unsigned bc[4];
    __shared__ float bf[1];

    const int tid = threadIdx.x;
    const float* cp = ce_part + tid * 8;
    double n_ = (double)cp[0];
    double d_ = (double)cp[1];
    unsigned a = ((const unsigned*)cp)[2];
    unsigned b = ((const unsigned*)cp)[3];
    unsigned c = ((const unsigned*)cp)[4];
    for (int off = 32; off > 0; off >>= 1) {
        n_ += __shfl_down(n_, off);
        d_ += __shfl_down(d_, off);
        a  += __shfl_down(a, off);
        b  += __shfl_down(b, off);
        c  += __shfl_down(c, off);
    }
    const int wid = tid >> 6;
    if ((tid & 63) == 0) { sd[wid] = n_; sd[8 + wid] = d_;
                           su[wid] = a; su[8 + wid] = b; su[16 + wid] = c; }
    __syncthreads();
    if (tid == 0) {
        double tn = 0.0, td = 0.0;
        unsigned ta = 0u, tb = 0u, tc = 0u;
        for (int w = 0; w < 8; ++w) {
            tn += sd[w]; td += sd[8 + w];
            ta += su[w]; tb += su[8 + w]; tc += su[16 + w];
        }
        ws_d[0] = tn; ws_d[1] = td;
        ws_u[4] = ta; ws_u[5] = tb;
        float nf = (float)((int)ta - 1);
        float pos = fmaxf(0.75f * nf, 0.0f);
        float lo = floorf(pos);
        bf[0] = pos - lo;
        bc[0] = tc;
        bc[2] = (unsigned)lo;
        bc[3] = (unsigned)ceilf(pos);
    }
    __syncthreads();
    const unsigned zadd = bc[0];
    const unsigned r0 = bc[2], r1 = bc[3];
    if (tid == 0) ws_f[7] = bf[0];

    scan_search_g(gh1, 2048, r0, zadd, sv, wsb, ret);
    if (tid == 0) { ws_u[8] = ret[0]; ws_u[10] = ret[1]; }
    scan_search_g(gh1, 2048, r1, zadd, sv, wsb, ret);
    if (tid == 0) { ws_u[9] = ret[0]; ws_u[11] = ret[1]; }
}

// ---------------- histogram passes 2 and 3 ----------------
__device__ __forceinline__ void h2_one(unsigned key, unsigned p0, unsigned p1,
                                       unsigned* h)
{
    unsigned top = key >> 21;
    unsigned sub = (key >> 10) & 2047u;
    if (top == p0) atomicAdd(&h[sub], 1u);
    if (top == p1) atomicAdd(&h[2048 + sub], 1u);
}

extern "C" __global__ __launch_bounds__(256)
void k_hist2(const unsigned* __restrict__ keys, const float2* __restrict__ xzw,
             const int* __restrict__ mask, const int* __restrict__ widx,
             int use_keys, int n, const unsigned* __restrict__ ws_u,
             unsigned* __restrict__ gh)
{
    __shared__ unsigned h[2 * 2048];
    for (int j = threadIdx.x; j < 2 * 2048; j += 256) h[j] = 0u;
    __syncthreads();
    const unsigned p0 = ws_u[8], p1 = ws_u[9];
    const int nthr = gridDim.x * blockDim.x;
    const int gtid = blockIdx.x * blockDim.x + threadIdx.x;
    const int nq = n >> 2;
    if (use_keys) {
        const uint4* k4 = (const uint4*)keys;
        int base = gtid;
        for (; base + 3 * nthr < nq; base += 4 * nthr) {
            uint4 a = k4[base], b = k4[base + nthr];
            uint4 c = k4[base + 2 * nthr], d = k4[base + 3 * nthr];
            h2_one(a.x, p0, p1, h); h2_one(a.y, p0, p1, h);
            h2_one(a.z, p0, p1, h); h2_one(a.w, p0, p1, h);
            h2_one(b.x, p0, p1, h); h2_one(b.y, p0, p1, h);
            h2_one(b.z, p0, p1, h); h2_one(b.w, p0, p1, h);
            h2_one(c.x, p0, p1, h); h2_one(c.y, p0, p1, h);
            h2_one(c.z, p0, p1, h); h2_one(c.w, p0, p1, h);
            h2_one(d.x, p0, p1, h); h2_one(d.y, p0, p1, h);
            h2_one(d.z, p0, p1, h); h2_one(d.w, p0, p1, h);
        }
        for (; base < nq; base += nthr) {
            uint4 a = k4[base];
            h2_one(a.x, p0, p1, h); h2_one(a.y, p0, p1, h);
            h2_one(a.z, p0, p1, h); h2_one(a.w, p0, p1, h);
        }
        for (int i = (nq << 2) + gtid; i < n; i += nthr)
            h2_one(keys[i], p0, p1, h);
    } else {
        for (int i = gtid; i < n; i += nthr)
            h2_one(make_key_raw(xzw, mask, widx, i), p0, p1, h);
    }
    __syncthreads();
    for (int j = threadIdx.x; j < 2 * 2048; j += 256)
        if (h[j]) atomicAdd(&gh[j], h[j]);
}

extern "C" __global__ __launch_bounds__(256)
void k_scan2(unsigned* __restrict__ ws_u, const unsigned* __restrict__ gh)
{
    __shared__ unsigned sv[2048];
    __shared__ unsigned wsb[16];
    __shared__ unsigned ret[2];
    unsigned p0 = ws_u[8], p1 = ws_u[9];
    unsigned r0 = ws_u[10], r1 = ws_u[11];
    scan_search_g(gh, 2048, r0, 0u, sv, wsb, ret);
    if (threadIdx.x == 0) { ws_u[8] = (p0 << 11) | ret[0]; ws_u[10] = ret[1]; }
    scan_search_g(gh + 2048, 2048, r1, 0u, sv, wsb, ret);
    if (threadIdx.x == 0) { ws_u[9] = (p1 << 11) | ret[0]; ws_u[11] = ret[1]; }
}

__device__ __forceinline__ void h3_one(unsigned key, unsigned p0, unsigned p1,
                                       unsigned* h)
{
    unsigned top = key >> 10;
    unsigned sub = key & 1023u;
    if (top == p0) atomicAdd(&h[sub], 1u);
    if (top == p1) atomicAdd(&h[1024 + sub], 1u);
}

extern "C" __global__ __launch_bounds__(256)
void k_hist3(const unsigned* __restrict__ keys, const float2* __restrict__ xzw,
             const int* __restrict__ mask, const int* __restrict__ widx,
             int use_keys, int n, const unsigned* __restrict__ ws_u,
             unsigned* __restrict__ gh)
{
    __shared__ unsigned h[2 * 1024];
    for (int j = threadIdx.x; j < 2 * 1024; j += 256) h[j] = 0u;
    __syncthreads();
    const unsigned p0 = ws_u[8], p1 = ws_u[9];
    const int nthr = gridDim.x * blockDim.x;
    const int gtid = blockIdx.x * blockDim.x + threadIdx.x;
    const int nq = n >> 2;
    if (use_keys) {
        const uint4* k4 = (const uint4*)keys;
        int base = gtid;
        for (; base + 3 * nthr < nq; base += 4 * nthr) {
            uint4 a = k4[base], b = k4[base + nthr];
            uint4 c = k4[base + 2 * nthr], d = k4[base + 3 * nthr];
            h3_one(a.x, p0, p1, h); h3_one(a.y, p0, p1, h);
            h3_one(a.z, p0, p1, h); h3_one(a.w, p0, p1, h);
            h3_one(b.x, p0, p1, h); h3_one(b.y, p0, p1, h);
            h3_one(b.z, p0, p1, h); h3_one(b.w, p0, p1, h);
            h3_one(c.x, p0, p1, h); h3_one(c.y, p0, p1, h);
            h3_one(c.z, p0, p1, h); h3_one(c.w, p0, p1, h);
            h3_one(d.x, p0, p1, h); h3_one(d.y, p0, p1, h);
            h3_one(d.z, p0, p1, h); h3_one(d.w, p0, p1, h);
        }
        for (; base < nq; base += nthr) {
            uint4 a = k4[base];
            h3_one(a.x, p0, p1, h); h3_one(a.y, p0, p1, h);
            h3_one(a.z, p0, p1, h); h3_one(a.w, p0, p1, h);
        }
        for (int i = (nq << 2) + gtid; i < n; i += nthr)
            h3_one(keys[i], p0, p1, h);
    } else {
        for (int i = gtid; i < n; i += nthr)
            h3_one(make_key_raw(xzw, mask, widx, i), p0, p1, h);
    }
    __syncthreads();
    for (int j = threadIdx.x; j < 2 * 1024; j += 256)
        if (h[j]) atomicAdd(&gh[j], h[j]);
}

// ---------------- finalize: fused scan3 + window loss ----------------
extern "C" __global__ __launch_bounds__(1024)
void k_final(const unsigned* __restrict__ g_seg_u32, const double* __restrict__ ws_d,
             const float* __restrict__ ws_f, const unsigned* __restrict__ ws_u,
             const unsigned* __restrict__ gh3, float* __restrict__ out)
{
    __shared__ unsigned sv[1024];
    __shared__ unsigned wsb[16];
    __shared__ unsigned ret[2];
    __shared__ double red[48];

    const unsigned p0 = ws_u[8], p1 = ws_u[9];
    const unsigned r0 = ws_u[10], r1 = ws_u[11];
    scan_search_g(gh3, 1024, r0, 0u, sv, wsb, ret);
    const float v0 = __uint_as_float((p0 << 10) | ret[0]);
    scan_search_g(gh3 + 1024, 1024, r1, 0u, sv, wsb, ret);
    const float v1 = __uint_as_float((p1 << 10) | ret[0]);

    const int nvalid = (int)ws_u[4];
    const float frac = ws_f[7];
    const float qf = v0 * (1.0f - frac) + v1 * frac;
    const double ref = (double)((nvalid > 0) ? fmaxf(qf, EPSF) : 1.0f);

    const uint4* gs4 = (const uint4*)g_seg_u32;
    double ninc = 0.0, fsum = 0.0, lsum = 0.0;
    for (int w = threadIdx.x; w < NWIN; w += blockDim.x) {
        uint4 v = gs4[w];
        double c   = (double)v.x;
        double sp  = (double)v.y * INV_P;
        double ar  = (double)v.z * INV_R;
        double spd = (double)v.w * INV_R;
        double inc = (c >= 2.0 && sp >= 1e-6) ? 1.0 : 0.0;
        double dmean = spd / (sp + 1e-6);
        double rr = ar / (1000.0 + 1e-6);
        double bu = fmax(rr - 1.0, 0.0);
        double flow = bu * bu;
        double rho = fmin(fmax(rr, 0.0), 0.99);
        double dth = 1.0 / (1.0 - rho + 1e-6);
        double lat = fmax(dth - dmean / ref, 0.0);
        ninc += inc; fsum += flow * inc; lsum += lat * inc;
    }
    for (int off = 32; off > 0; off >>= 1) {
        ninc += __shfl_down(ninc, off);
        fsum += __shfl_down(fsum, off);
        lsum += __shfl_down(lsum, off);
    }
    int wid = threadIdx.x >> 6, lane = threadIdx.x & 63;
    if (lane == 0) { red[wid] = ninc; red[16 + wid] = fsum; red[32 + wid] = lsum; }
    __syncthreads();
    if (threadIdx.x == 0) {
        double n_i = 0.0, f_s = 0.0, l_s = 0.0;
        int nw = (int)blockDim.x >> 6;
        for (int w = 0; w < nw; ++w) { n_i += red[w]; f_s += red[16 + w]; l_s += red[32 + w]; }
        double safe = fmax(n_i, 1.0);
        double l_flow = (n_i > 0.0) ? f_s / safe : 0.0;
        double l_lat  = (n_i > 0.0) ? l_s / safe : 0.0;
        double den = ws_d[1];
        double l_data = ws_d[0] / fmax(den, 1e-12);
        bool any = ws_u[5] > 0u;
        if (!any) { l_data = 0.0; l_flow = 0.0; l_lat = 0.0; }
        out[0] = (float)(l_data + 0.1 * l_flow + 0.1 * l_lat);
        out[1] = (float)l_data;
        out[2] = (float)l_flow;
        out[3] = (float)l_lat;
    }
}

extern "C" void kernel_launch(void* const* d_in, const int* in_sizes, int n_in,
                              void* d_out, int out_size, void* d_ws, size_t ws_size,
                              hipStream_t stream)
{
    const float2* logits = (const float2*)d_in[0];
    const int* y = (const int*)d_in[1];
    const int* mask = (const int*)d_in[2];       // bool delivered as int32
    const float2* xzw = (const float2*)d_in[3];  // x_raw viewed as float2 pairs
    const int* widx = (const int*)d_in[4];
    const float* cw = (const float*)d_in[5];
    float* out = (float*)d_out;
    const int n = in_sizes[1];   // N from y

    unsigned char* ws8 = (unsigned char*)d_ws;
    double* ws_d = (double*)ws8;
    float* ws_f = (float*)ws8;
    unsigned* ws_u = (unsigned*)ws8;
    unsigned* g_seg_u32 = (unsigned*)(ws8 + OFF_SEGU);
    unsigned* g_h1 = (unsigned*)(ws8 + OFF_H1);
    unsigned* g_h2 = (unsigned*)(ws8 + OFF_H2);
    unsigned* g_h3 = (unsigned*)(ws8 + OFF_H3);
    float* ce_part = (float*)(ws8 + OFF_CEP);

    const size_t part_bytes = (size_t)GRID_MAIN * SEGW * 4u;     // 25.2 MB
    const size_t keys_bytes = (size_t)n * 4u;                    // 16.8 MB
    size_t off = OFF_PART;
    int use_part = 0, use_keys = 0;
    unsigned* part = (unsigned*)(ws8 + off);
    if (ws_size >= off + part_bytes) { use_part = 1; off += part_bytes; }
    unsigned* keys = (unsigned*)(ws8 + off);
    if (ws_size >= off + keys_bytes) { use_keys = 1; }

    hipMemsetAsync(d_ws, 0, OFF_PART, stream);   // header + g_seg_u32 + hists + cep

    k_main<<<GRID_MAIN, BLOCK_MAIN, 0, stream>>>(logits, y, mask, xzw, widx, cw,
                                                 ce_part, g_seg_u32, part, keys,
                                                 g_h1, use_part, use_keys, n);
    k_post<<<97, 512, 0, stream>>>(part, g_seg_u32, ce_part, ws_d, ws_u, ws_f,
                                   g_h1, use_part);
    k_hist2<<<1024, 256, 0, stream>>>(keys, xzw, mask, widx, use_keys, n, ws_u, g_h2);
    k_scan2<<<1, 256, 0, stream>>>(ws_u, g_h2);
    k_hist3<<<1024, 256, 0, stream>>>(keys, xzw, mask, widx, use_keys, n, ws_u, g_h3);
    k_final<<<1, 1024, 0, stream>>>(g_seg_u32, ws_d, ws_f, ws_u, g_h3, out);
}

// Round 15
// 91.793 us; speedup vs baseline: 1.6237x; 1.2536x over previous
//
#include <hip/hip_runtime.h>

#define NWIN 4096
#define EPSF 1e-6f
#define GRID_MAIN 512
#define BLOCK_MAIN 512
#define NWAVES (BLOCK_MAIN / 64)

// fixed-point scales (u32 LDS atomics; native ds_add_u32)
#define SCALE_P   2097152.0f     // 2^21  sum_p
#define SCALE_R   131072.0f      // 2^17  agg_rate / sum_pd
#define INV_P     (1.0/2097152.0)
#define INV_R     (1.0/131072.0)

// ---------------- workspace layout (bytes) ----------------
//  byte 0:  double ce_num     byte 8:  double ce_den
//  byte 16: u32 n_valid(u[4]) byte 20: u32 n_mask(u[5])
//  byte 24: f32 ref_dobs(f[6]) byte 28: f32 frac(f[7])
//  byte 32,36: u32 prefixes (u[8],u[9])  byte 40,44: u32 ranks (u[10],u[11])
#define OFF_SEGU  256            // u32 g_seg_u32[16384] interleaved [wi*4+c]
#define OFF_H1    65792          // u32[2048]
#define OFF_H2    73984          // u32[2*2048]
#define OFF_H3    90368          // u32[2*1024]
#define OFF_CEP   98560          // float ce_part[512*8] (16 KB)
#define OFF_PART  131072         // part(32MB) | keys

__device__ __forceinline__ unsigned make_key_raw(const float2* __restrict__ xzw,
                                                 const int* __restrict__ mask,
                                                 const int* __restrict__ widx, int i)
{
    int wi = widx[i];
    int m = mask[i];
    if (wi < 0 || !m) return 0x7F800000u;
    float d = fmaxf(xzw[2 * i + 1].x, 0.0f);
    unsigned k = __float_as_uint(d);
    return (k == 0x80000000u) ? 0u : k;
}

// ---------------- per-element fused work (branchless) ----------------
__device__ __forceinline__ void process_elem(
    float lgx, float lgy, int yi, int mi, float xz, float xw, int wi,
    float cw0, float cw1, unsigned* keyOut,
    float& num, float& den, unsigned& nv, unsigned& nm, unsigned& zc,
    unsigned* s_seg, unsigned* s_h1)
{
    float d = lgx - lgy;
    float ad = fabsf(d);
    float t = __expf(-ad);
    float inv1t = 1.0f / (1.0f + t);
    float l1p = __logf(1.0f + t);
    float s = yi ? d : -d;
    float nll = fmaxf(s, 0.0f) + l1p;
    float maskf = mi ? 1.0f : 0.0f;
    float wy = (yi ? cw1 : cw0) * maskf;
    nm += (mi != 0);
    num += wy * nll;
    den += wy;

    bool vq = (wi >= 0) && mi;
    float dob = fmaxf(xz, 0.0f);
    unsigned kraw = __float_as_uint(dob);
    kraw = (kraw == 0x80000000u) ? 0u : kraw;
    unsigned key = vq ? kraw : 0x7F800000u;
    *keyOut = key;
    nv += vq;
    zc += (key == 0u);

    atomicAdd(&s_h1[key >> 21], (key != 0u) ? 1u : 0u);

    bool sv = vq && ((unsigned)wi < NWIN);
    float sf = sv ? 1.0f : 0.0f;
    unsigned b = sv ? ((unsigned)wi << 2) : (4u * NWIN);
    float p = ((d > 0.0f) ? t : 1.0f) * inv1t;
    float rate = fmaxf(xw, 0.0f);
    atomicAdd(&s_seg[b],     sv ? 1u : 0u);
    atomicAdd(&s_seg[b | 1], (unsigned)(sf * p * SCALE_P + 0.5f));
    atomicAdd(&s_seg[b | 2], (unsigned)(sf * p * rate * SCALE_R + 0.5f));
    atomicAdd(&s_seg[b | 3], (unsigned)(sf * p * dob * SCALE_R + 0.5f));
}

// ---------------- main fused pass (NO global atomics to shared lines) ----------------
extern "C" __global__ __launch_bounds__(BLOCK_MAIN)
void k_main(const float2* __restrict__ logits, const int* __restrict__ y,
            const int* __restrict__ mask, const float2* __restrict__ xzw,
            const int* __restrict__ widx, const float* __restrict__ cw,
            float* __restrict__ ce_part,
            unsigned* __restrict__ g_seg_u32, unsigned* __restrict__ part,
            unsigned* __restrict__ keys, unsigned* __restrict__ gh1,
            int use_part, int use_keys, int n)
{
    __shared__ unsigned s_seg[4 * NWIN + 4];   // 64 KB + dummy slot
    __shared__ unsigned s_h1[2048];            // 8 KB level-1 histogram
    __shared__ float s_redf[2 * NWAVES];
    __shared__ unsigned s_redu[3 * NWAVES];
    for (int j = threadIdx.x; j < 4 * NWIN + 4; j += BLOCK_MAIN) s_seg[j] = 0u;
    for (int j = threadIdx.x; j < 2048; j += BLOCK_MAIN) s_h1[j] = 0u;
    __syncthreads();

    const float cw0 = cw[0], cw1 = cw[1];
    float num = 0.0f, den = 0.0f;
    unsigned nv = 0u, nm = 0u, zc = 0u;

    const int nth = GRID_MAIN * BLOCK_MAIN;
    const int gtid = blockIdx.x * BLOCK_MAIN + threadIdx.x;
    const int nq = n >> 2;

    const float4* lg4 = (const float4*)logits;
    const int4* y4p = (const int4*)y;
    const int4* m4p = (const int4*)mask;
    const int4* w4p = (const int4*)widx;

    for (int q = gtid; q < nq; q += nth) {
        float4 lgA = lg4[2 * q], lgB = lg4[2 * q + 1];
        int4 y4 = y4p[q], m4 = m4p[q], w4 = w4p[q];
        float2 z0 = xzw[8 * q + 1], z1 = xzw[8 * q + 3];
        float2 z2 = xzw[8 * q + 5], z3 = xzw[8 * q + 7];

        uint4 kq;
        process_elem(lgA.x, lgA.y, y4.x, m4.x, z0.x, z0.y, w4.x,
                     cw0, cw1, &kq.x, num, den, nv, nm, zc, s_seg, s_h1);
        process_elem(lgA.z, lgA.w, y4.y, m4.y, z1.x, z1.y, w4.y,
                     cw0, cw1, &kq.y, num, den, nv, nm, zc, s_seg, s_h1);
        process_elem(lgB.x, lgB.y, y4.z, m4.z, z2.x, z2.y, w4.z,
                     cw0, cw1, &kq.z, num, den, nv, nm, zc, s_seg, s_h1);
        process_elem(lgB.z, lgB.w, y4.w, m4.w, z3.x, z3.y, w4.w,
                     cw0, cw1, &kq.w, num, den, nv, nm, zc, s_seg, s_h1);
        if (use_keys) ((uint4*)keys)[q] = kq;
    }
    for (int i = (nq << 2) + gtid; i < n; i += nth) {   // tail (n%4)
        float2 lg = logits[i];
        float2 zz = xzw[2 * i + 1];
        unsigned k;
        process_elem(lg.x, lg.y, y[i], mask[i], zz.x, zz.y, widx[i],
                     cw0, cw1, &k, num, den, nv, nm, zc, s_seg, s_h1);
        if (use_keys) keys[i] = k;
    }

    // wave(64) shuffle reduce -> LDS -> one private-slot store per block
    for (int off = 32; off > 0; off >>= 1) {
        num += __shfl_down(num, off);
        den += __shfl_down(den, off);
        nv  += __shfl_down(nv, off);
        nm  += __shfl_down(nm, off);
        zc  += __shfl_down(zc, off);
    }
    const int wid = threadIdx.x >> 6;
    if ((threadIdx.x & 63) == 0) {
        s_redf[wid] = num; s_redf[NWAVES + wid] = den;
        s_redu[wid] = nv; s_redu[NWAVES + wid] = nm; s_redu[2 * NWAVES + wid] = zc;
    }
    __syncthreads();
    if (threadIdx.x == 0) {
        float tn = 0.0f, td = 0.0f;
        unsigned ta = 0u, tb = 0u, tc = 0u;
        for (int w = 0; w < NWAVES; ++w) {
            tn += s_redf[w]; td += s_redf[NWAVES + w];
            ta += s_redu[w]; tb += s_redu[NWAVES + w]; tc += s_redu[2 * NWAVES + w];
        }
        float* cp = ce_part + blockIdx.x * 8;
        cp[0] = tn; cp[1] = td;
        ((unsigned*)cp)[2] = ta; ((unsigned*)cp)[3] = tb; ((unsigned*)cp)[4] = tc;
    }

    if (use_part) {
        uint4* dst = (uint4*)(part + (size_t)blockIdx.x * (4 * NWIN));
        const uint4* src = (const uint4*)s_seg;
        for (int j = threadIdx.x; j < NWIN; j += BLOCK_MAIN) dst[j] = src[j];
    } else {
        for (int j = threadIdx.x; j < 4 * NWIN; j += BLOCK_MAIN) {
            unsigned v = s_seg[j];
            if (v) atomicAdd(&g_seg_u32[j], v);
        }
    }
    for (int j = threadIdx.x; j < 2048; j += BLOCK_MAIN) {
        unsigned v = s_h1[j];
        if (v) atomicAdd(&gh1[j], v);   // ~60 distinct bins/block: fast pattern
    }
}

// ---------------- generic block-wide scan + rank search ----------------
__device__ void scan_search_g(const unsigned* __restrict__ gh, int NB, unsigned rank,
                              unsigned zadd, unsigned* sv, unsigned* wsb,
                              unsigned* ret)
{
    const int tid = threadIdx.x;
    const int B = blockDim.x;
    for (int j = tid; j < NB; j += B) sv[j] = gh[j] + ((j == 0) ? zadd : 0u);
    __syncthreads();
    const int E = NB / B;
    const int base = tid * E;
    unsigned loc = 0u;
    for (int e = 0; e < E; ++e) loc += sv[base + e];
    unsigned inc = loc;
    const int lane = tid & 63;
    for (int off = 1; off < 64; off <<= 1) {
        unsigned u = __shfl_up(inc, off);
        if (lane >= off) inc += u;
    }
    const int wid = tid >> 6;
    const int nw = B >> 6;
    if (lane == 63) wsb[wid] = inc;
    __syncthreads();
    if (tid == 0) {
        unsigned run = 0u;
        for (int w = 0; w < nw; ++w) { unsigned t = wsb[w]; wsb[w] = run; run += t; }
    }
    __syncthreads();
    unsigned c = wsb[wid] + (inc - loc);
    for (int e = 0; e < E; ++e) {
        unsigned hv = sv[base + e];
        if (rank >= c && rank < c + hv) { ret[0] = (unsigned)(base + e); ret[1] = rank - c; }
        c += hv;
    }
    __syncthreads();
}

// ---------------- fused post pass: blocks 0-127 reduce partials; block 128 CE+scan1 ----------------
extern "C" __global__ __launch_bounds__(512)
void k_post(const unsigned* __restrict__ part, unsigned* __restrict__ g_seg_u32,
            const float* __restrict__ ce_part, double* __restrict__ ws_d,
            unsigned* __restrict__ ws_u, float* __restrict__ ws_f,
            const unsigned* __restrict__ gh1, int use_part)
{
    if (blockIdx.x < 128) {
        if (!use_part) return;
        // chunk c in 0..3, bin group g in 0..31 -> bin = g*512 + tid
        const int c = blockIdx.x >> 5;
        const int bin = (blockIdx.x & 31) * 512 + threadIdx.x;
        const unsigned* p = part + (size_t)c * 128 * (4 * NWIN) + bin;
        unsigned s = 0u;
#pragma unroll 8
        for (int b = 0; b < 128; ++b) s += p[(size_t)b * (4 * NWIN)];
        if (s) atomicAdd(&g_seg_u32[bin], s);
        return;
    }

    // ---- block 128: CE finalize + level-1 scan ----
    __shared__ unsigned sv[2048];
    __shared__ unsigned wsb[16];
    __shared__ unsigned ret[2];
    __shared__ double sd[2 * 8];
    __shared__ unsigned su[3 * 8];
    __shared__ unsigned bc[4];       // zc_total, n_valid, rank0, rank1
    __shared__ float bf[1];          // frac

    const int tid = threadIdx.x;
    const float* cp = ce_part + tid * 8;
    double n_ = (double)cp[0];
    double d_ = (double)cp[1];
    unsigned a = ((const unsigned*)cp)[2];
    unsigned b = ((const unsigned*)cp)[3];
    unsigned c = ((const unsigned*)cp)[4];
    for (int off = 32; off > 0; off >>= 1) {
        n_ += __shfl_down(n_, off);
        d_ += __shfl_down(d_, off);
        a  += __shfl_down(a, off);
        b  += __shfl_down(b, off);
        c  += __shfl_down(c, off);
    }
    const int wid = tid >> 6;
    if ((tid & 63) == 0) { sd[wid] = n_; sd[8 + wid] = d_;
                           su[wid] = a; su[8 + wid] = b; su[16 + wid] = c; }
    __syncthreads();
    if (tid == 0) {
        double tn = 0.0, td = 0.0;
        unsigned ta = 0u, tb = 0u, tc = 0u;
        for (int w = 0; w < 8; ++w) {
            tn += sd[w]; td += sd[8 + w];
            ta += su[w]; tb += su[8 + w]; tc += su[16 + w];
        }
        ws_d[0] = tn; ws_d[1] = td;
        ws_u[4] = ta; ws_u[5] = tb;
        float nf = (float)((int)ta - 1);
        float pos = fmaxf(0.75f * nf, 0.0f);
        float lo = floorf(pos);
        bf[0] = pos - lo;
        bc[0] = tc;                          // zc total
        bc[1] = ta;                          // n_valid
        bc[2] = (unsigned)lo;                // rank0
        bc[3] = (unsigned)ceilf(pos);        // rank1
    }
    __syncthreads();
    const unsigned zadd = bc[0];
    const unsigned r0 = bc[2], r1 = bc[3];
    if (tid == 0) ws_f[7] = bf[0];

    scan_search_g(gh1, 2048, r0, zadd, sv, wsb, ret);
    if (tid == 0) { ws_u[8] = ret[0]; ws_u[10] = ret[1]; }
    scan_search_g(gh1, 2048, r1, zadd, sv, wsb, ret);
    if (tid == 0) { ws_u[9] = ret[0]; ws_u[11] = ret[1]; }
}

// ---------------- histogram passes 2 and 3 ----------------
__device__ __forceinline__ void h2_one(unsigned key, unsigned p0, unsigned p1,
                                       unsigned* h)
{
    unsigned top = key >> 21;
    unsigned sub = (key >> 10) & 2047u;
    if (top == p0) atomicAdd(&h[sub], 1u);
    if (top == p1) atomicAdd(&h[2048 + sub], 1u);
}

extern "C" __global__ __launch_bounds__(256)
void k_hist2(const unsigned* __restrict__ keys, const float2* __restrict__ xzw,
             const int* __restrict__ mask, const int* __restrict__ widx,
             int use_keys, int n, const unsigned* __restrict__ ws_u,
             unsigned* __restrict__ gh)
{
    __shared__ unsigned h[2 * 2048];
    for (int j = threadIdx.x; j < 2 * 2048; j += 256) h[j] = 0u;
    __syncthreads();
    const unsigned p0 = ws_u[8], p1 = ws_u[9];
    const int nthr = gridDim.x * blockDim.x;
    const int gtid = blockIdx.x * blockDim.x + threadIdx.x;
    const int nq = n >> 2;
    if (use_keys) {
        const uint4* k4 = (const uint4*)keys;
        int base = gtid;
        for (; base + 3 * nthr < nq; base += 4 * nthr) {
            uint4 a = k4[base], b = k4[base + nthr];
            uint4 c = k4[base + 2 * nthr], d = k4[base + 3 * nthr];
            h2_one(a.x, p0, p1, h); h2_one(a.y, p0, p1, h);
            h2_one(a.z, p0, p1, h); h2_one(a.w, p0, p1, h);
            h2_one(b.x, p0, p1, h); h2_one(b.y, p0, p1, h);
            h2_one(b.z, p0, p1, h); h2_one(b.w, p0, p1, h);
            h2_one(c.x, p0, p1, h); h2_one(c.y, p0, p1, h);
            h2_one(c.z, p0, p1, h); h2_one(c.w, p0, p1, h);
            h2_one(d.x, p0, p1, h); h2_one(d.y, p0, p1, h);
            h2_one(d.z, p0, p1, h); h2_one(d.w, p0, p1, h);
        }
        for (; base < nq; base += nthr) {
            uint4 a = k4[base];
            h2_one(a.x, p0, p1, h); h2_one(a.y, p0, p1, h);
            h2_one(a.z, p0, p1, h); h2_one(a.w, p0, p1, h);
        }
        for (int i = (nq << 2) + gtid; i < n; i += nthr)
            h2_one(keys[i], p0, p1, h);
    } else {
        for (int i = gtid; i < n; i += nthr)
            h2_one(make_key_raw(xzw, mask, widx, i), p0, p1, h);
    }
    __syncthreads();
    for (int j = threadIdx.x; j < 2 * 2048; j += 256)
        if (h[j]) atomicAdd(&gh[j], h[j]);
}

extern "C" __global__ __launch_bounds__(256)
void k_scan2(unsigned* __restrict__ ws_u, const unsigned* __restrict__ gh)
{
    __shared__ unsigned sv[2048];
    __shared__ unsigned wsb[16];
    __shared__ unsigned ret[2];
    unsigned p0 = ws_u[8], p1 = ws_u[9];
    unsigned r0 = ws_u[10], r1 = ws_u[11];
    scan_search_g(gh, 2048, r0, 0u, sv, wsb, ret);
    if (threadIdx.x == 0) { ws_u[8] = (p0 << 11) | ret[0]; ws_u[10] = ret[1]; }
    scan_search_g(gh + 2048, 2048, r1, 0u, sv, wsb, ret);
    if (threadIdx.x == 0) { ws_u[9] = (p1 << 11) | ret[0]; ws_u[11] = ret[1]; }
}

__device__ __forceinline__ void h3_one(unsigned key, unsigned p0, unsigned p1,
                                       unsigned* h)
{
    unsigned top = key >> 10;
    unsigned sub = key & 1023u;
    if (top == p0) atomicAdd(&h[sub], 1u);
    if (top == p1) atomicAdd(&h[1024 + sub], 1u);
}

extern "C" __global__ __launch_bounds__(256)
void k_hist3(const unsigned* __restrict__ keys, const float2* __restrict__ xzw,
             const int* __restrict__ mask, const int* __restrict__ widx,
             int use_keys, int n, const unsigned* __restrict__ ws_u,
             unsigned* __restrict__ gh)
{
    __shared__ unsigned h[2 * 1024];
    for (int j = threadIdx.x; j < 2 * 1024; j += 256) h[j] = 0u;
    __syncthreads();
    const unsigned p0 = ws_u[8], p1 = ws_u[9];
    const int nthr = gridDim.x * blockDim.x;
    const int gtid = blockIdx.x * blockDim.x + threadIdx.x;
    const int nq = n >> 2;
    if (use_keys) {
        const uint4* k4 = (const uint4*)keys;
        int base = gtid;
        for (; base + 3 * nthr < nq; base += 4 * nthr) {
            uint4 a = k4[base], b = k4[base + nthr];
            uint4 c = k4[base + 2 * nthr], d = k4[base + 3 * nthr];
            h3_one(a.x, p0, p1, h); h3_one(a.y, p0, p1, h);
            h3_one(a.z, p0, p1, h); h3_one(a.w, p0, p1, h);
            h3_one(b.x, p0, p1, h); h3_one(b.y, p0, p1, h);
            h3_one(b.z, p0, p1, h); h3_one(b.w, p0, p1, h);
            h3_one(c.x, p0, p1, h); h3_one(c.y, p0, p1, h);
            h3_one(c.z, p0, p1, h); h3_one(c.w, p0, p1, h);
            h3_one(d.x, p0, p1, h); h3_one(d.y, p0, p1, h);
            h3_one(d.z, p0, p1, h); h3_one(d.w, p0, p1, h);
        }
        for (; base < nq; base += nthr) {
            uint4 a = k4[base];
            h3_one(a.x, p0, p1, h); h3_one(a.y, p0, p1, h);
            h3_one(a.z, p0, p1, h); h3_one(a.w, p0, p1, h);
        }
        for (int i = (nq << 2) + gtid; i < n; i += nthr)
            h3_one(keys[i], p0, p1, h);
    } else {
        for (int i = gtid; i < n; i += nthr)
            h3_one(make_key_raw(xzw, mask, widx, i), p0, p1, h);
    }
    __syncthreads();
    for (int j = threadIdx.x; j < 2 * 1024; j += 256)
        if (h[j]) atomicAdd(&gh[j], h[j]);
}

// ---------------- finalize: fused scan3 + window loss (1024 threads) ----------------
extern "C" __global__ __launch_bounds__(1024)
void k_final(const unsigned* __restrict__ g_seg_u32, const double* __restrict__ ws_d,
             const float* __restrict__ ws_f, const unsigned* __restrict__ ws_u,
             const unsigned* __restrict__ gh3, float* __restrict__ out)
{
    __shared__ unsigned sv[1024];
    __shared__ unsigned wsb[16];
    __shared__ unsigned ret[2];
    __shared__ double red[48];

    // ---- scan3 (all 1024 threads; E = 1) ----
    const unsigned p0 = ws_u[8], p1 = ws_u[9];
    const unsigned r0 = ws_u[10], r1 = ws_u[11];
    scan_search_g(gh3, 1024, r0, 0u, sv, wsb, ret);
    const float v0 = __uint_as_float((p0 << 10) | ret[0]);
    scan_search_g(gh3 + 1024, 1024, r1, 0u, sv, wsb, ret);
    const float v1 = __uint_as_float((p1 << 10) | ret[0]);

    const int nvalid = (int)ws_u[4];
    const float frac = ws_f[7];
    const float qf = v0 * (1.0f - frac) + v1 * frac;
    const double ref = (double)((nvalid > 0) ? fmaxf(qf, EPSF) : 1.0f);

    // ---- per-window physics terms (g_seg_u32 converted inline) ----
    const uint4* gs4 = (const uint4*)g_seg_u32;
    double ninc = 0.0, fsum = 0.0, lsum = 0.0;
    for (int w = threadIdx.x; w < NWIN; w += blockDim.x) {
        uint4 v = gs4[w];
        double c   = (double)v.x;
        double sp  = (double)v.y * INV_P;
        double ar  = (double)v.z * INV_R;
        double spd = (double)v.w * INV_R;
        double inc = (c >= 2.0 && sp >= 1e-6) ? 1.0 : 0.0;
        double dmean = spd / (sp + 1e-6);
        double rr = ar / (1000.0 + 1e-6);
        double bu = fmax(rr - 1.0, 0.0);
        double flow = bu * bu;
        double rho = fmin(fmax(rr, 0.0), 0.99);
        double dth = 1.0 / (1.0 - rho + 1e-6);
        double lat = fmax(dth - dmean / ref, 0.0);
        ninc += inc; fsum += flow * inc; lsum += lat * inc;
    }
    for (int off = 32; off > 0; off >>= 1) {
        ninc += __shfl_down(ninc, off);
        fsum += __shfl_down(fsum, off);
        lsum += __shfl_down(lsum, off);
    }
    int wid = threadIdx.x >> 6, lane = threadIdx.x & 63;
    if (lane == 0) { red[wid] = ninc; red[16 + wid] = fsum; red[32 + wid] = lsum; }
    __syncthreads();
    if (threadIdx.x == 0) {
        double n_i = 0.0, f_s = 0.0, l_s = 0.0;
        int nw = (int)blockDim.x >> 6;
        for (int w = 0; w < nw; ++w) { n_i += red[w]; f_s += red[16 + w]; l_s += red[32 + w]; }
        double safe = fmax(n_i, 1.0);
        double l_flow = (n_i > 0.0) ? f_s / safe : 0.0;
        double l_lat  = (n_i > 0.0) ? l_s / safe : 0.0;
        double den = ws_d[1];
        double l_data = ws_d[0] / fmax(den, 1e-12);
        bool any = ws_u[5] > 0u;
        if (!any) { l_data = 0.0; l_flow = 0.0; l_lat = 0.0; }
        out[0] = (float)(l_data + 0.1 * l_flow + 0.1 * l_lat);
        out[1] = (float)l_data;
        out[2] = (float)l_flow;
        out[3] = (float)l_lat;
    }
}

extern "C" void kernel_launch(void* const* d_in, const int* in_sizes, int n_in,
                              void* d_out, int out_size, void* d_ws, size_t ws_size,
                              hipStream_t stream)
{
    const float2* logits = (const float2*)d_in[0];
    const int* y = (const int*)d_in[1];
    const int* mask = (const int*)d_in[2];       // bool delivered as int32
    const float2* xzw = (const float2*)d_in[3];  // x_raw viewed as float2 pairs
    const int* widx = (const int*)d_in[4];
    const float* cw = (const float*)d_in[5];
    float* out = (float*)d_out;
    const int n = in_sizes[1];   // N from y

    unsigned char* ws8 = (unsigned char*)d_ws;
    double* ws_d = (double*)ws8;
    float* ws_f = (float*)ws8;
    unsigned* ws_u = (unsigned*)ws8;
    unsigned* g_seg_u32 = (unsigned*)(ws8 + OFF_SEGU);
    unsigned* g_h1 = (unsigned*)(ws8 + OFF_H1);
    unsigned* g_h2 = (unsigned*)(ws8 + OFF_H2);
    unsigned* g_h3 = (unsigned*)(ws8 + OFF_H3);
    float* ce_part = (float*)(ws8 + OFF_CEP);

    const size_t part_bytes = (size_t)GRID_MAIN * 4 * NWIN * 4;  // 32 MB
    const size_t keys_bytes = (size_t)n * 4u;                    // 16.8 MB
    size_t off = OFF_PART;
    int use_part = 0, use_keys = 0;
    unsigned* part = (unsigned*)(ws8 + off);
    if (ws_size >= off + part_bytes) { use_part = 1; off += part_bytes; }
    unsigned* keys = (unsigned*)(ws8 + off);
    if (ws_size >= off + keys_bytes) { use_keys = 1; }

    hipMemsetAsync(d_ws, 0, OFF_PART, stream);   // header + g_seg_u32 + hists + cep

    k_main<<<GRID_MAIN, BLOCK_MAIN, 0, stream>>>(logits, y, mask, xzw, widx, cw,
                                                 ce_part, g_seg_u32, part, keys,
                                                 g_h1, use_part, use_keys, n);
    k_post<<<129, 512, 0, stream>>>(part, g_seg_u32, ce_part, ws_d, ws_u, ws_f,
                                    g_h1, use_part);
    k_hist2<<<1024, 256, 0, stream>>>(keys, xzw, mask, widx, use_keys, n, ws_u, g_h2);
    k_scan2<<<1, 256, 0, stream>>>(ws_u, g_h2);
    k_hist3<<<1024, 256, 0, stream>>>(keys, xzw, mask, widx, use_keys, n, ws_u, g_h3);
    k_final<<<1, 1024, 0, stream>>>(g_seg_u32, ws_d, ws_f, ws_u, g_h3, out);
}